// Round 13
// baseline (387.512 us; speedup 1.0000x reference)
//
#include <hip/hip_runtime.h>
#include <hip/hip_fp16.h>

#define NEG_SLOPE 0.2f

typedef __attribute__((ext_vector_type(8))) _Float16 f16x8;
typedef __attribute__((ext_vector_type(2))) _Float16 f16x2;
typedef __attribute__((ext_vector_type(4))) float f32x4;

__device__ __forceinline__ void gload_lds16(const unsigned short* g, unsigned short* lds) {
    __builtin_amdgcn_global_load_lds(
        (const __attribute__((address_space(1))) void*)g,
        (__attribute__((address_space(3))) void*)lds, 16, 0, 0);
}

__device__ __forceinline__ f16x2 habs2(f16x2 v) {
    unsigned int u = __builtin_bit_cast(unsigned int, v) & 0x7FFF7FFFu;
    return __builtin_bit_cast(f16x2, u);
}

// ---------------------------------------------------------------------------
// CSR build
// ---------------------------------------------------------------------------

__global__ void detect_i64_kernel(const unsigned int* __restrict__ w, int E, int* __restrict__ flag) {
    __shared__ unsigned int ssum[256];
    int n = E < 4096 ? E : 4096;
    unsigned int local = 0;
    for (int k = threadIdx.x; k < n; k += 256) local |= w[2 * k + 1];
    ssum[threadIdx.x] = local;
    __syncthreads();
    for (int off = 128; off > 0; off >>= 1) {
        if (threadIdx.x < off) ssum[threadIdx.x] |= ssum[threadIdx.x + off];
        __syncthreads();
    }
    if (threadIdx.x == 0) flag[0] = (ssum[0] == 0) ? 1 : 0;
}

__global__ void count_deg_kernel(const void* __restrict__ eiv, int E,
                                 const int* __restrict__ flag, int* __restrict__ deg) {
    int e = blockIdx.x * blockDim.x + threadIdx.x;
    if (e >= E) return;
    int d;
    if (*flag) d = (int)((const long long*)eiv)[(size_t)E + e];
    else       d = ((const int*)eiv)[(size_t)E + e];
    atomicAdd(&deg[d], 1);
}

__global__ void scan_block_kernel(const int* __restrict__ deg, int* __restrict__ row_ptr,
                                  int* __restrict__ partial, int N) {
    __shared__ int sd[1024];
    int t = threadIdx.x;
    int g = blockIdx.x * 1024 + t;
    int v = (g < N) ? deg[g] : 0;
    sd[t] = v;
    __syncthreads();
    for (int off = 1; off < 1024; off <<= 1) {
        int add = (t >= off) ? sd[t - off] : 0;
        __syncthreads();
        sd[t] += add;
        __syncthreads();
    }
    if (g < N) row_ptr[g + 1] = sd[t];
    if (t == 1023) partial[blockIdx.x] = sd[1023];
    if (g == 0) row_ptr[0] = 0;
}

__global__ void scan_top_kernel(int* __restrict__ partial, int nb) {
    if (threadIdx.x == 0 && blockIdx.x == 0) {
        int run = 0;
        for (int j = 0; j < nb; ++j) { run += partial[j]; partial[j] = run; }
    }
}

__global__ void scan_addoff_kernel(int* __restrict__ row_ptr, const int* __restrict__ partial, int N) {
    int g = blockIdx.x * 256 + threadIdx.x;
    if (g >= N) return;
    int b = g >> 10;
    if (b > 0) row_ptr[g + 1] += partial[b - 1];
}

__global__ void scatter_kernel(const void* __restrict__ eiv, int E,
                               const int* __restrict__ flag,
                               const int* __restrict__ row_ptr,
                               int* __restrict__ cursor, int* __restrict__ csr) {
    int e = blockIdx.x * blockDim.x + threadIdx.x;
    if (e >= E) return;
    int s, d;
    if (*flag) {
        s = (int)((const long long*)eiv)[e];
        d = (int)((const long long*)eiv)[(size_t)E + e];
    } else {
        s = ((const int*)eiv)[e];
        d = ((const int*)eiv)[(size_t)E + e];
    }
    int pos = atomicAdd(&cursor[d], 1);
    csr[row_ptr[d] + pos] = s;
}

// ---------------------------------------------------------------------------
// fp32 -> fp16 convert (A operand, layer 1); weights -> fp16 transposed
// ---------------------------------------------------------------------------

__global__ void to_f16_kernel(const float* __restrict__ src, int n4,
                              unsigned short* __restrict__ dst) {
    int i = blockIdx.x * blockDim.x + threadIdx.x;
    if (i >= n4) return;
    float4 v = *reinterpret_cast<const float4*>(&src[(size_t)i * 4]);
    ushort4 h;
    h.x = __half_as_ushort(__float2half(v.x));
    h.y = __half_as_ushort(__float2half(v.y));
    h.z = __half_as_ushort(__float2half(v.z));
    h.w = __half_as_ushort(__float2half(v.w));
    *reinterpret_cast<ushort4*>(&dst[(size_t)i * 4]) = h;
}

__global__ void splitT_w_kernel(const float* __restrict__ Wl, const float* __restrict__ Wr, int M,
                                unsigned short* __restrict__ WT) {
    int k = blockIdx.x;
    int m2 = blockIdx.y * 256 + threadIdx.x;
    if (m2 >= 2 * M) return;
    float v = (m2 < M) ? Wl[(size_t)k * M + m2] : Wr[(size_t)k * M + (m2 - M)];
    WT[(size_t)m2 * 256 + k] = __half_as_ushort(__float2half(v));
}

// ---------------------------------------------------------------------------
// MFMA GEMM: plain fp16 single-pass. Tile 128x128, BK=64, single-buffered LDS
// (32 KB: A, B), gload_lds staging with pre-swizzled global source (R7/R11
// proven). 128 MFMA/wave. Epilogue: cols [0,M) -> fp16 xl; [M,2M) -> fp32 xr.
// ---------------------------------------------------------------------------

__global__ __launch_bounds__(256) void gemm_mfma_kernel(
    const unsigned short* __restrict__ A, const unsigned short* __restrict__ B,
    __half* __restrict__ xl16, float* __restrict__ xr32, int N, int M) {
    __shared__ unsigned short sA[128 * 64];
    __shared__ unsigned short sB[128 * 64];

    int t = threadIdx.x;
    int lane = t & 63;
    int w = t >> 6;
    int wr = (w >> 1) * 64;
    int wc = (w & 1) * 64;
    int row0 = blockIdx.x * 128;
    int n0 = blockIdx.y * 128;

    int l15 = lane & 15;
    int l4 = lane >> 4;

    int lr8 = lane >> 3;
    int lc8 = lane & 7;
    int ksw = (lc8 ^ lr8) * 8;

    f32x4 acc[4][4] = {};

    for (int k0 = 0; k0 < 256; k0 += 64) {
        __syncthreads();
        #pragma unroll
        for (int i = 0; i < 4; ++i) {
            int brow = i * 32 + w * 8;
            int row = brow + lr8;
            int ar = row0 + row; if (ar >= N) ar = N - 1;
            int bc = n0 + row;
            gload_lds16(&A[(size_t)ar * 256 + k0 + ksw], &sA[brow * 64]);
            gload_lds16(&B[(size_t)bc * 256 + k0 + ksw], &sB[brow * 64]);
        }
        __syncthreads();

        #pragma unroll
        for (int ksub = 0; ksub < 2; ++ksub) {
            int kb = ksub * 32 + l4 * 8;
            f16x8 b[4];
            #pragma unroll
            for (int fc = 0; fc < 4; ++fc) {
                int cc = wc + fc * 16 + l15;
                b[fc] = *reinterpret_cast<const f16x8*>(&sB[cc * 64 + (kb ^ ((cc & 7) << 3))]);
            }
            #pragma unroll
            for (int fr = 0; fr < 4; ++fr) {
                int r = wr + fr * 16 + l15;
                f16x8 a = *reinterpret_cast<const f16x8*>(&sA[r * 64 + (kb ^ ((r & 7) << 3))]);
                #pragma unroll
                for (int fc = 0; fc < 4; ++fc) {
                    acc[fr][fc] = __builtin_amdgcn_mfma_f32_16x16x32_f16(a, b[fc], acc[fr][fc], 0, 0, 0);
                }
            }
        }
    }

    #pragma unroll
    for (int fr = 0; fr < 4; ++fr) {
        #pragma unroll
        for (int j = 0; j < 4; ++j) {
            int row = row0 + wr + fr * 16 + l4 * 4 + j;
            if (row < N) {
                #pragma unroll
                for (int fc = 0; fc < 4; ++fc) {
                    int col = n0 + wc + fc * 16 + l15;
                    float v = acc[fr][fc][j];
                    if (col < M) xl16[(size_t)row * M + col] = __float2half(v);
                    else         xr32[(size_t)row * M + (col - M)] = v;
                }
            }
        }
    }
}

// ---------------------------------------------------------------------------
// agg_h8: one wave per node; half = lane>>5 picks edge slot, lane&31 owns
// 8 channels. Packed-fp16 logit via v_dot2_f32_f16, f32 acc, fixed-m softmax.
// 2-DEEP software pipeline: 3-stage register rotation, 8 edges in flight/wave.
// ---------------------------------------------------------------------------

__global__ __launch_bounds__(256) void agg_h8_kernel(
    const __half* __restrict__ xl16, const float* __restrict__ xr32,
    const float* __restrict__ att, const float* __restrict__ bias,
    const int* __restrict__ row_ptr, const int* __restrict__ csr,
    unsigned short* __restrict__ oh, int N) {
    int wv = threadIdx.x >> 6;
    int i = blockIdx.x * 4 + wv;
    if (i >= N) return;
    int lane = threadIdx.x & 63;
    int half = lane >> 5;
    int cb = (lane & 31) * 8;

    f16x2 r2[4], a62[4], a42[4];
    {
        float4 r0 = *reinterpret_cast<const float4*>(&xr32[(size_t)i * 256 + cb]);
        float4 r1 = *reinterpret_cast<const float4*>(&xr32[(size_t)i * 256 + cb + 4]);
        float rr[8] = {r0.x, r0.y, r0.z, r0.w, r1.x, r1.y, r1.z, r1.w};
        float4 w0 = *reinterpret_cast<const float4*>(&att[cb]);
        float4 w1 = *reinterpret_cast<const float4*>(&att[cb + 4]);
        float aa[8] = {w0.x, w0.y, w0.z, w0.w, w1.x, w1.y, w1.z, w1.w};
        #pragma unroll
        for (int j = 0; j < 4; ++j) {
            r2[j]  = f16x2{(_Float16)rr[2 * j], (_Float16)rr[2 * j + 1]};
            a62[j] = f16x2{(_Float16)(0.6f * aa[2 * j]), (_Float16)(0.6f * aa[2 * j + 1])};
            a42[j] = f16x2{(_Float16)(0.4f * aa[2 * j]), (_Float16)(0.4f * aa[2 * j + 1])};
        }
    }

    float acc[8], l, m;
    {
        uint4 sv = *reinterpret_cast<const uint4*>(&xl16[(size_t)i * 256 + cb]);
        const f16x2* u2 = reinterpret_cast<const f16x2*>(&sv);
        float p = 0.f;
        #pragma unroll
        for (int j = 0; j < 4; ++j) {
            f16x2 v2 = u2[j] + r2[j];
            p = __builtin_amdgcn_fdot2(a62[j], v2, p, false);
            p = __builtin_amdgcn_fdot2(a42[j], habs2(v2), p, false);
        }
        p += __shfl_xor(p, 1, 4);
        p += __shfl_xor(p, 2, 4);
        m = p;
        l = half ? 0.f : 1.f;
        #pragma unroll
        for (int j = 0; j < 4; ++j) {
            acc[2 * j]     = half ? 0.f : (float)u2[j][0];
            acc[2 * j + 1] = half ? 0.f : (float)u2[j][1];
        }
    }

    int start = row_ptr[i], end = row_ptr[i + 1];

    // 2-deep pipeline prologue: stages for iterations k, k+4
    #define LOAD_PAIR(A0, B0, base)                                              \
        {                                                                        \
            int kka = (base) + half, kkb = (base) + 2 + half;                    \
            int sa = (kka < end) ? csr[kka] : i;                                 \
            int sb = (kkb < end) ? csr[kkb] : i;                                 \
            A0 = *reinterpret_cast<const uint4*>(&xl16[(size_t)sa * 256 + cb]);  \
            B0 = *reinterpret_cast<const uint4*>(&xl16[(size_t)sb * 256 + cb]);  \
        }

    uint4 c0a, c0b, c1a, c1b;
    LOAD_PAIR(c0a, c0b, start);
    LOAD_PAIR(c1a, c1b, start + 4);

    for (int k = start; k < end; k += 4) {
        uint4 n2a, n2b;
        LOAD_PAIR(n2a, n2b, k + 8);

        const f16x2* ua2 = reinterpret_cast<const f16x2*>(&c0a);
        const f16x2* ub2 = reinterpret_cast<const f16x2*>(&c0b);
        float p0 = 0.f, p1 = 0.f;
        #pragma unroll
        for (int j = 0; j < 4; ++j) {
            f16x2 v0 = ua2[j] + r2[j];
            p0 = __builtin_amdgcn_fdot2(a62[j], v0, p0, false);
            p0 = __builtin_amdgcn_fdot2(a42[j], habs2(v0), p0, false);
            f16x2 v1 = ub2[j] + r2[j];
            p1 = __builtin_amdgcn_fdot2(a62[j], v1, p1, false);
            p1 = __builtin_amdgcn_fdot2(a42[j], habs2(v1), p1, false);
        }
        p0 += __shfl_xor(p0, 1, 4);
        p0 += __shfl_xor(p0, 2, 4);
        p1 += __shfl_xor(p1, 1, 4);
        p1 += __shfl_xor(p1, 2, 4);
        float e0 = (k + half < end)     ? __expf(fminf(p0 - m, 60.f)) : 0.f;
        float e1 = (k + 2 + half < end) ? __expf(fminf(p1 - m, 60.f)) : 0.f;
        l += e0 + e1;
        #pragma unroll
        for (int j = 0; j < 4; ++j) {
            acc[2 * j]     = fmaf(e0, (float)ua2[j][0], fmaf(e1, (float)ub2[j][0], acc[2 * j]));
            acc[2 * j + 1] = fmaf(e0, (float)ua2[j][1], fmaf(e1, (float)ub2[j][1], acc[2 * j + 1]));
        }

        c0a = c1a; c0b = c1b;
        c1a = n2a; c1b = n2b;
    }
    #undef LOAD_PAIR

    l += __shfl_xor(l, 32, 64);
    #pragma unroll
    for (int c = 0; c < 8; ++c) acc[c] += __shfl_xor(acc[c], 32, 64);

    if (half == 0) {
        float4 bb0 = *reinterpret_cast<const float4*>(&bias[cb]);
        float4 bb1 = *reinterpret_cast<const float4*>(&bias[cb + 4]);
        float bs[8] = {bb0.x, bb0.y, bb0.z, bb0.w, bb1.x, bb1.y, bb1.z, bb1.w};
        float inv = 1.0f / l;
        unsigned int hw[4];
        #pragma unroll
        for (int c2 = 0; c2 < 4; ++c2) {
            float r0 = fmaf(acc[2 * c2], inv, bs[2 * c2]);
            float r1 = fmaf(acc[2 * c2 + 1], inv, bs[2 * c2 + 1]);
            r0 = (r0 > 0.f) ? r0 : (__expf(r0) - 1.f);
            r1 = (r1 > 0.f) ? r1 : (__expf(r1) - 1.f);
            unsigned short h0 = __half_as_ushort(__float2half(r0));
            unsigned short h1 = __half_as_ushort(__float2half(r1));
            hw[c2] = (unsigned int)h0 | ((unsigned int)h1 << 16);
        }
        *reinterpret_cast<uint4*>(&oh[(size_t)i * 256 + cb]) = make_uint4(hw[0], hw[1], hw[2], hw[3]);
    }
}

// ---------------------------------------------------------------------------
// agg_h1 (layer 3): one wave per node, 8 edge slots x 8 lanes x 8 ch.
// Packed-fp16 logit, f32 acc, fixed-m softmax, 2-deep pipeline.
// ---------------------------------------------------------------------------

__global__ __launch_bounds__(256) void agg_h1_kernel(
    const __half* __restrict__ xl16, const float* __restrict__ xr32,
    const float* __restrict__ att, const float* __restrict__ bias,
    const int* __restrict__ row_ptr, const int* __restrict__ csr,
    float* __restrict__ out, int N) {
    int wv = threadIdx.x >> 6;
    int i = blockIdx.x * 4 + wv;
    if (i >= N) return;
    int lane = threadIdx.x & 63;
    int es = lane >> 3;
    int cb = (lane & 7) * 8;

    f16x2 r2[4], a62[4], a42[4];
    {
        float4 r0 = *reinterpret_cast<const float4*>(&xr32[(size_t)i * 64 + cb]);
        float4 r1 = *reinterpret_cast<const float4*>(&xr32[(size_t)i * 64 + cb + 4]);
        float rr[8] = {r0.x, r0.y, r0.z, r0.w, r1.x, r1.y, r1.z, r1.w};
        float4 w0 = *reinterpret_cast<const float4*>(&att[cb]);
        float4 w1 = *reinterpret_cast<const float4*>(&att[cb + 4]);
        float aa[8] = {w0.x, w0.y, w0.z, w0.w, w1.x, w1.y, w1.z, w1.w};
        #pragma unroll
        for (int j = 0; j < 4; ++j) {
            r2[j]  = f16x2{(_Float16)rr[2 * j], (_Float16)rr[2 * j + 1]};
            a62[j] = f16x2{(_Float16)(0.6f * aa[2 * j]), (_Float16)(0.6f * aa[2 * j + 1])};
            a42[j] = f16x2{(_Float16)(0.4f * aa[2 * j]), (_Float16)(0.4f * aa[2 * j + 1])};
        }
    }

    float acc[8], l, m;
    {
        uint4 sv = *reinterpret_cast<const uint4*>(&xl16[(size_t)i * 64 + cb]);
        const f16x2* u2 = reinterpret_cast<const f16x2*>(&sv);
        float p = 0.f;
        #pragma unroll
        for (int j = 0; j < 4; ++j) {
            f16x2 v2 = u2[j] + r2[j];
            p = __builtin_amdgcn_fdot2(a62[j], v2, p, false);
            p = __builtin_amdgcn_fdot2(a42[j], habs2(v2), p, false);
        }
        p += __shfl_xor(p, 1, 8);
        p += __shfl_xor(p, 2, 8);
        p += __shfl_xor(p, 4, 8);
        m = p;
        l = es ? 0.f : 1.f;
        #pragma unroll
        for (int j = 0; j < 4; ++j) {
            acc[2 * j]     = es ? 0.f : (float)u2[j][0];
            acc[2 * j + 1] = es ? 0.f : (float)u2[j][1];
        }
    }

    int start = row_ptr[i], end = row_ptr[i + 1];

    #define LOAD_ONE(DST, base)                                                  \
        {                                                                        \
            int kkx = (base) + es;                                               \
            int sx = (kkx < end) ? csr[kkx] : i;                                 \
            DST = *reinterpret_cast<const uint4*>(&xl16[(size_t)sx * 64 + cb]);  \
        }

    uint4 c0, c1;
    LOAD_ONE(c0, start);
    LOAD_ONE(c1, start + 8);

    for (int k = start; k < end; k += 8) {
        uint4 n2;
        LOAD_ONE(n2, k + 16);

        const f16x2* u2 = reinterpret_cast<const f16x2*>(&c0);
        float p = 0.f;
        #pragma unroll
        for (int j = 0; j < 4; ++j) {
            f16x2 v2 = u2[j] + r2[j];
            p = __builtin_amdgcn_fdot2(a62[j], v2, p, false);
            p = __builtin_amdgcn_fdot2(a42[j], habs2(v2), p, false);
        }
        p += __shfl_xor(p, 1, 8);
        p += __shfl_xor(p, 2, 8);
        p += __shfl_xor(p, 4, 8);
        float e = (k + es < end) ? __expf(fminf(p - m, 60.f)) : 0.f;
        l += e;
        #pragma unroll
        for (int j = 0; j < 4; ++j) {
            acc[2 * j]     = fmaf(e, (float)u2[j][0], acc[2 * j]);
            acc[2 * j + 1] = fmaf(e, (float)u2[j][1], acc[2 * j + 1]);
        }

        c0 = c1; c1 = n2;
    }
    #undef LOAD_ONE

    l += __shfl_xor(l, 8, 64);
    l += __shfl_xor(l, 16, 64);
    l += __shfl_xor(l, 32, 64);
    #pragma unroll
    for (int c = 0; c < 8; ++c) {
        acc[c] += __shfl_xor(acc[c], 8, 64);
        acc[c] += __shfl_xor(acc[c], 16, 64);
        acc[c] += __shfl_xor(acc[c], 32, 64);
    }

    if (es == 0) {
        float inv = 1.0f / l;
        float4 bb0 = *reinterpret_cast<const float4*>(&bias[cb]);
        float4 bb1 = *reinterpret_cast<const float4*>(&bias[cb + 4]);
        float4 o0, o1;
        o0.x = fmaf(acc[0], inv, bb0.x);
        o0.y = fmaf(acc[1], inv, bb0.y);
        o0.z = fmaf(acc[2], inv, bb0.z);
        o0.w = fmaf(acc[3], inv, bb0.w);
        o1.x = fmaf(acc[4], inv, bb1.x);
        o1.y = fmaf(acc[5], inv, bb1.y);
        o1.z = fmaf(acc[6], inv, bb1.z);
        o1.w = fmaf(acc[7], inv, bb1.w);
        *reinterpret_cast<float4*>(&out[(size_t)i * 64 + cb]) = o0;
        *reinterpret_cast<float4*>(&out[(size_t)i * 64 + cb + 4]) = o1;
    }
}

// ---------------------------------------------------------------------------

extern "C" void kernel_launch(void* const* d_in, const int* in_sizes, int n_in,
                              void* d_out, int out_size, void* d_ws, size_t ws_size,
                              hipStream_t stream) {
    const float* x    = (const float*)d_in[0];
    const void*  ei   = d_in[1];
    const float* Wl1  = (const float*)d_in[2];
    const float* Wr1  = (const float*)d_in[3];
    const float* att1 = (const float*)d_in[4];
    const float* b1   = (const float*)d_in[5];
    const float* Wl2  = (const float*)d_in[6];
    const float* Wr2  = (const float*)d_in[7];
    const float* att2 = (const float*)d_in[8];
    const float* b2   = (const float*)d_in[9];
    const float* Wl3  = (const float*)d_in[10];
    const float* Wr3  = (const float*)d_in[11];
    const float* att3 = (const float*)d_in[12];
    const float* b3   = (const float*)d_in[13];
    float* out = (float*)d_out;

    int N = in_sizes[0] / 256;
    int E = in_sizes[1] / 2;

    char* w = (char*)d_ws;
    unsigned short* a16  = (unsigned short*)w; w += (size_t)N * 256 * 2;  // GEMM A operand
    __half* xl16 = (__half*)w;     w += (size_t)N * 256 * 2;
    float* xr32 = (float*)w;       w += (size_t)N * 256 * sizeof(float);
    unsigned short* WT = (unsigned short*)w; w += (size_t)512 * 256 * 2;
    int* row_ptr = (int*)w; w += ((size_t)N + 2) * sizeof(int);
    int* deg     = (int*)w; w += (size_t)N * sizeof(int);
    int* csr     = (int*)w; w += (size_t)E * sizeof(int);
    int* flag    = (int*)w; w += 256;
    int* partial = (int*)w; w += 256;

    // --- CSR build ---
    detect_i64_kernel<<<1, 256, 0, stream>>>((const unsigned int*)ei, E, flag);
    hipMemsetAsync(deg, 0, (size_t)N * sizeof(int), stream);
    count_deg_kernel<<<(E + 255) / 256, 256, 0, stream>>>(ei, E, flag, deg);
    int nb = (N + 1023) / 1024;
    scan_block_kernel<<<nb, 1024, 0, stream>>>(deg, row_ptr, partial, N);
    scan_top_kernel<<<1, 64, 0, stream>>>(partial, nb);
    scan_addoff_kernel<<<(N + 255) / 256, 256, 0, stream>>>(row_ptr, partial, N);
    hipMemsetAsync(deg, 0, (size_t)N * sizeof(int), stream);
    scatter_kernel<<<(E + 255) / 256, 256, 0, stream>>>(ei, E, flag, row_ptr, deg, csr);

    int gemm_gx = (N + 127) / 128;
    int agg_g = (N + 3) / 4;

    // --- Layer 1 ---
    to_f16_kernel<<<((N * 256 / 4) + 255) / 256, 256, 0, stream>>>(x, N * 256 / 4, a16);
    splitT_w_kernel<<<dim3(256, 2), 256, 0, stream>>>(Wl1, Wr1, 256, WT);
    gemm_mfma_kernel<<<dim3(gemm_gx, 4), 256, 0, stream>>>(a16, WT, xl16, xr32, N, 256);
    agg_h8_kernel<<<agg_g, 256, 0, stream>>>(xl16, xr32, att1, b1, row_ptr, csr, a16, N);

    // --- Layer 2 ---
    splitT_w_kernel<<<dim3(256, 2), 256, 0, stream>>>(Wl2, Wr2, 256, WT);
    gemm_mfma_kernel<<<dim3(gemm_gx, 4), 256, 0, stream>>>(a16, WT, xl16, xr32, N, 256);
    agg_h8_kernel<<<agg_g, 256, 0, stream>>>(xl16, xr32, att2, b2, row_ptr, csr, a16, N);

    // --- Layer 3 ---
    splitT_w_kernel<<<dim3(256, 1), 256, 0, stream>>>(Wl3, Wr3, 64, WT);
    gemm_mfma_kernel<<<dim3(gemm_gx, 1), 256, 0, stream>>>(a16, WT, xl16, xr32, N, 64);
    agg_h1_kernel<<<agg_g, 256, 0, stream>>>(xl16, xr32, att3, b3, row_ptr, csr, out, N);
}

// Round 14
// 361.979 us; speedup vs baseline: 1.0705x; 1.0705x over previous
//
#include <hip/hip_runtime.h>
#include <hip/hip_fp16.h>

#define NEG_SLOPE 0.2f

typedef __attribute__((ext_vector_type(8))) _Float16 f16x8;
typedef __attribute__((ext_vector_type(2))) _Float16 f16x2;
typedef __attribute__((ext_vector_type(4))) float f32x4;

__device__ __forceinline__ void gload_lds16(const unsigned short* g, unsigned short* lds) {
    __builtin_amdgcn_global_load_lds(
        (const __attribute__((address_space(1))) void*)g,
        (__attribute__((address_space(3))) void*)lds, 16, 0, 0);
}

__device__ __forceinline__ f16x2 habs2(f16x2 v) {
    unsigned int u = __builtin_bit_cast(unsigned int, v) & 0x7FFF7FFFu;
    return __builtin_bit_cast(f16x2, u);
}

// ---------------------------------------------------------------------------
// CSR build
// ---------------------------------------------------------------------------

__global__ void detect_i64_kernel(const unsigned int* __restrict__ w, int E, int* __restrict__ flag) {
    __shared__ unsigned int ssum[256];
    int n = E < 4096 ? E : 4096;
    unsigned int local = 0;
    for (int k = threadIdx.x; k < n; k += 256) local |= w[2 * k + 1];
    ssum[threadIdx.x] = local;
    __syncthreads();
    for (int off = 128; off > 0; off >>= 1) {
        if (threadIdx.x < off) ssum[threadIdx.x] |= ssum[threadIdx.x + off];
        __syncthreads();
    }
    if (threadIdx.x == 0) flag[0] = (ssum[0] == 0) ? 1 : 0;
}

__global__ void count_deg_kernel(const void* __restrict__ eiv, int E,
                                 const int* __restrict__ flag, int* __restrict__ deg) {
    int e = blockIdx.x * blockDim.x + threadIdx.x;
    if (e >= E) return;
    int d;
    if (*flag) d = (int)((const long long*)eiv)[(size_t)E + e];
    else       d = ((const int*)eiv)[(size_t)E + e];
    atomicAdd(&deg[d], 1);
}

__global__ void scan_block_kernel(const int* __restrict__ deg, int* __restrict__ row_ptr,
                                  int* __restrict__ partial, int N) {
    __shared__ int sd[1024];
    int t = threadIdx.x;
    int g = blockIdx.x * 1024 + t;
    int v = (g < N) ? deg[g] : 0;
    sd[t] = v;
    __syncthreads();
    for (int off = 1; off < 1024; off <<= 1) {
        int add = (t >= off) ? sd[t - off] : 0;
        __syncthreads();
        sd[t] += add;
        __syncthreads();
    }
    if (g < N) row_ptr[g + 1] = sd[t];
    if (t == 1023) partial[blockIdx.x] = sd[1023];
    if (g == 0) row_ptr[0] = 0;
}

__global__ void scan_top_kernel(int* __restrict__ partial, int nb) {
    if (threadIdx.x == 0 && blockIdx.x == 0) {
        int run = 0;
        for (int j = 0; j < nb; ++j) { run += partial[j]; partial[j] = run; }
    }
}

__global__ void scan_addoff_kernel(int* __restrict__ row_ptr, const int* __restrict__ partial, int N) {
    int g = blockIdx.x * 256 + threadIdx.x;
    if (g >= N) return;
    int b = g >> 10;
    if (b > 0) row_ptr[g + 1] += partial[b - 1];
}

__global__ void scatter_kernel(const void* __restrict__ eiv, int E,
                               const int* __restrict__ flag,
                               const int* __restrict__ row_ptr,
                               int* __restrict__ cursor, int* __restrict__ csr) {
    int e = blockIdx.x * blockDim.x + threadIdx.x;
    if (e >= E) return;
    int s, d;
    if (*flag) {
        s = (int)((const long long*)eiv)[e];
        d = (int)((const long long*)eiv)[(size_t)E + e];
    } else {
        s = ((const int*)eiv)[e];
        d = ((const int*)eiv)[(size_t)E + e];
    }
    int pos = atomicAdd(&cursor[d], 1);
    csr[row_ptr[d] + pos] = s;
}

// ---------------------------------------------------------------------------
// fp32 -> fp16 convert (A operand, layer 1); weights -> fp16 transposed
// ---------------------------------------------------------------------------

__global__ void to_f16_kernel(const float* __restrict__ src, int n4,
                              unsigned short* __restrict__ dst) {
    int i = blockIdx.x * blockDim.x + threadIdx.x;
    if (i >= n4) return;
    float4 v = *reinterpret_cast<const float4*>(&src[(size_t)i * 4]);
    ushort4 h;
    h.x = __half_as_ushort(__float2half(v.x));
    h.y = __half_as_ushort(__float2half(v.y));
    h.z = __half_as_ushort(__float2half(v.z));
    h.w = __half_as_ushort(__float2half(v.w));
    *reinterpret_cast<ushort4*>(&dst[(size_t)i * 4]) = h;
}

__global__ void splitT_w_kernel(const float* __restrict__ Wl, const float* __restrict__ Wr, int M,
                                unsigned short* __restrict__ WT) {
    int k = blockIdx.x;
    int m2 = blockIdx.y * 256 + threadIdx.x;
    if (m2 >= 2 * M) return;
    float v = (m2 < M) ? Wl[(size_t)k * M + m2] : Wr[(size_t)k * M + (m2 - M)];
    WT[(size_t)m2 * 256 + k] = __half_as_ushort(__float2half(v));
}

// ---------------------------------------------------------------------------
// MFMA GEMM: plain fp16 single-pass. Tile 128x128, BK=64, single-buffered LDS
// (32 KB: A, B), gload_lds staging with pre-swizzled global source (R7/R11
// proven). 128 MFMA/wave. Epilogue: unified fp16 C [N][2M] (xl | xr halves).
// ---------------------------------------------------------------------------

__global__ __launch_bounds__(256) void gemm_mfma_kernel(
    const unsigned short* __restrict__ A, const unsigned short* __restrict__ B,
    __half* __restrict__ C16, int N, int M) {
    __shared__ unsigned short sA[128 * 64];
    __shared__ unsigned short sB[128 * 64];

    int t = threadIdx.x;
    int lane = t & 63;
    int w = t >> 6;
    int wr = (w >> 1) * 64;
    int wc = (w & 1) * 64;
    int row0 = blockIdx.x * 128;
    int n0 = blockIdx.y * 128;
    int ldc = 2 * M;

    int l15 = lane & 15;
    int l4 = lane >> 4;

    int lr8 = lane >> 3;
    int lc8 = lane & 7;
    int ksw = (lc8 ^ lr8) * 8;

    f32x4 acc[4][4] = {};

    for (int k0 = 0; k0 < 256; k0 += 64) {
        __syncthreads();
        #pragma unroll
        for (int i = 0; i < 4; ++i) {
            int brow = i * 32 + w * 8;
            int row = brow + lr8;
            int ar = row0 + row; if (ar >= N) ar = N - 1;
            int bc = n0 + row;
            gload_lds16(&A[(size_t)ar * 256 + k0 + ksw], &sA[brow * 64]);
            gload_lds16(&B[(size_t)bc * 256 + k0 + ksw], &sB[brow * 64]);
        }
        __syncthreads();

        #pragma unroll
        for (int ksub = 0; ksub < 2; ++ksub) {
            int kb = ksub * 32 + l4 * 8;
            f16x8 b[4];
            #pragma unroll
            for (int fc = 0; fc < 4; ++fc) {
                int cc = wc + fc * 16 + l15;
                b[fc] = *reinterpret_cast<const f16x8*>(&sB[cc * 64 + (kb ^ ((cc & 7) << 3))]);
            }
            #pragma unroll
            for (int fr = 0; fr < 4; ++fr) {
                int r = wr + fr * 16 + l15;
                f16x8 a = *reinterpret_cast<const f16x8*>(&sA[r * 64 + (kb ^ ((r & 7) << 3))]);
                #pragma unroll
                for (int fc = 0; fc < 4; ++fc) {
                    acc[fr][fc] = __builtin_amdgcn_mfma_f32_16x16x32_f16(a, b[fc], acc[fr][fc], 0, 0, 0);
                }
            }
        }
    }

    #pragma unroll
    for (int fr = 0; fr < 4; ++fr) {
        #pragma unroll
        for (int j = 0; j < 4; ++j) {
            int row = row0 + wr + fr * 16 + l4 * 4 + j;
            if (row < N) {
                #pragma unroll
                for (int fc = 0; fc < 4; ++fc) {
                    int col = n0 + wc + fc * 16 + l15;
                    C16[(size_t)row * ldc + col] = __float2half(acc[fr][fc][j]);
                }
            }
        }
    }
}

// ---------------------------------------------------------------------------
// agg_h8: one wave per node; half = lane>>5 picks edge slot, lane&31 owns
// 8 channels. All-fp16 C [N][512] (xl cols 0-255, xr cols 256-511). Packed
// fp16 logit via v_dot2_f32_f16 (rxr used directly as loaded bits — zero
// conversion), f32 acc, fixed-m softmax, 1-deep pipeline (R12-proven).
// ---------------------------------------------------------------------------

__global__ __launch_bounds__(256) void agg_h8_kernel(
    const __half* __restrict__ C16,
    const float* __restrict__ att, const float* __restrict__ bias,
    const int* __restrict__ row_ptr, const int* __restrict__ csr,
    unsigned short* __restrict__ oh, int N) {
    int wv = threadIdx.x >> 6;
    int i = blockIdx.x * 4 + wv;
    if (i >= N) return;
    int lane = threadIdx.x & 63;
    int half = lane >> 5;
    int cb = (lane & 31) * 8;

    f16x2 r2[4], a62[4], a42[4];
    {
        uint4 rv = *reinterpret_cast<const uint4*>(&C16[(size_t)i * 512 + 256 + cb]);
        const f16x2* rp = reinterpret_cast<const f16x2*>(&rv);
        float4 w0 = *reinterpret_cast<const float4*>(&att[cb]);
        float4 w1 = *reinterpret_cast<const float4*>(&att[cb + 4]);
        float aa[8] = {w0.x, w0.y, w0.z, w0.w, w1.x, w1.y, w1.z, w1.w};
        #pragma unroll
        for (int j = 0; j < 4; ++j) {
            r2[j]  = rp[j];
            a62[j] = f16x2{(_Float16)(0.6f * aa[2 * j]), (_Float16)(0.6f * aa[2 * j + 1])};
            a42[j] = f16x2{(_Float16)(0.4f * aa[2 * j]), (_Float16)(0.4f * aa[2 * j + 1])};
        }
    }

    float acc[8], l, m;
    {
        uint4 sv = *reinterpret_cast<const uint4*>(&C16[(size_t)i * 512 + cb]);
        const f16x2* u2 = reinterpret_cast<const f16x2*>(&sv);
        float p = 0.f;
        #pragma unroll
        for (int j = 0; j < 4; ++j) {
            f16x2 v2 = u2[j] + r2[j];
            p = __builtin_amdgcn_fdot2(a62[j], v2, p, false);
            p = __builtin_amdgcn_fdot2(a42[j], habs2(v2), p, false);
        }
        p += __shfl_xor(p, 1, 4);
        p += __shfl_xor(p, 2, 4);
        m = p;
        l = half ? 0.f : 1.f;
        #pragma unroll
        for (int j = 0; j < 4; ++j) {
            acc[2 * j]     = half ? 0.f : (float)u2[j][0];
            acc[2 * j + 1] = half ? 0.f : (float)u2[j][1];
        }
    }

    int start = row_ptr[i], end = row_ptr[i + 1];

    int kk0 = start + half, kk1 = start + 2 + half;
    int s0 = (kk0 < end) ? csr[kk0] : i;
    int s1 = (kk1 < end) ? csr[kk1] : i;
    uint4 ca = *reinterpret_cast<const uint4*>(&C16[(size_t)s0 * 512 + cb]);
    uint4 cbv = *reinterpret_cast<const uint4*>(&C16[(size_t)s1 * 512 + cb]);

    for (int k = start; k < end; k += 4) {
        int nk0 = k + 4 + half, nk1 = k + 6 + half;
        int t0 = (nk0 < end) ? csr[nk0] : i;
        int t1 = (nk1 < end) ? csr[nk1] : i;
        uint4 na = *reinterpret_cast<const uint4*>(&C16[(size_t)t0 * 512 + cb]);
        uint4 nb = *reinterpret_cast<const uint4*>(&C16[(size_t)t1 * 512 + cb]);

        const f16x2* ua2 = reinterpret_cast<const f16x2*>(&ca);
        const f16x2* ub2 = reinterpret_cast<const f16x2*>(&cbv);
        float p0 = 0.f, p1 = 0.f;
        #pragma unroll
        for (int j = 0; j < 4; ++j) {
            f16x2 v0 = ua2[j] + r2[j];
            p0 = __builtin_amdgcn_fdot2(a62[j], v0, p0, false);
            p0 = __builtin_amdgcn_fdot2(a42[j], habs2(v0), p0, false);
            f16x2 v1 = ub2[j] + r2[j];
            p1 = __builtin_amdgcn_fdot2(a62[j], v1, p1, false);
            p1 = __builtin_amdgcn_fdot2(a42[j], habs2(v1), p1, false);
        }
        p0 += __shfl_xor(p0, 1, 4);
        p0 += __shfl_xor(p0, 2, 4);
        p1 += __shfl_xor(p1, 1, 4);
        p1 += __shfl_xor(p1, 2, 4);
        float e0 = (k + half < end)     ? __expf(fminf(p0 - m, 60.f)) : 0.f;
        float e1 = (k + 2 + half < end) ? __expf(fminf(p1 - m, 60.f)) : 0.f;
        l += e0 + e1;
        #pragma unroll
        for (int j = 0; j < 4; ++j) {
            acc[2 * j]     = fmaf(e0, (float)ua2[j][0], fmaf(e1, (float)ub2[j][0], acc[2 * j]));
            acc[2 * j + 1] = fmaf(e0, (float)ua2[j][1], fmaf(e1, (float)ub2[j][1], acc[2 * j + 1]));
        }

        ca = na; cbv = nb;
    }

    l += __shfl_xor(l, 32, 64);
    #pragma unroll
    for (int c = 0; c < 8; ++c) acc[c] += __shfl_xor(acc[c], 32, 64);

    if (half == 0) {
        float4 bb0 = *reinterpret_cast<const float4*>(&bias[cb]);
        float4 bb1 = *reinterpret_cast<const float4*>(&bias[cb + 4]);
        float bs[8] = {bb0.x, bb0.y, bb0.z, bb0.w, bb1.x, bb1.y, bb1.z, bb1.w};
        float inv = 1.0f / l;
        unsigned int hw[4];
        #pragma unroll
        for (int c2 = 0; c2 < 4; ++c2) {
            float r0 = fmaf(acc[2 * c2], inv, bs[2 * c2]);
            float r1 = fmaf(acc[2 * c2 + 1], inv, bs[2 * c2 + 1]);
            r0 = (r0 > 0.f) ? r0 : (__expf(r0) - 1.f);
            r1 = (r1 > 0.f) ? r1 : (__expf(r1) - 1.f);
            unsigned short h0 = __half_as_ushort(__float2half(r0));
            unsigned short h1 = __half_as_ushort(__float2half(r1));
            hw[c2] = (unsigned int)h0 | ((unsigned int)h1 << 16);
        }
        *reinterpret_cast<uint4*>(&oh[(size_t)i * 256 + cb]) = make_uint4(hw[0], hw[1], hw[2], hw[3]);
    }
}

// ---------------------------------------------------------------------------
// agg_h1 (layer 3): one wave per node, 8 edge slots x 8 lanes x 8 ch.
// C [N][128] fp16 (xl 0-63, xr 64-127). Packed-fp16 logit, f32 acc, fixed-m
// softmax, 1-deep pipeline. Output fp32.
// ---------------------------------------------------------------------------

__global__ __launch_bounds__(256) void agg_h1_kernel(
    const __half* __restrict__ C16,
    const float* __restrict__ att, const float* __restrict__ bias,
    const int* __restrict__ row_ptr, const int* __restrict__ csr,
    float* __restrict__ out, int N) {
    int wv = threadIdx.x >> 6;
    int i = blockIdx.x * 4 + wv;
    if (i >= N) return;
    int lane = threadIdx.x & 63;
    int es = lane >> 3;
    int cb = (lane & 7) * 8;

    f16x2 r2[4], a62[4], a42[4];
    {
        uint4 rv = *reinterpret_cast<const uint4*>(&C16[(size_t)i * 128 + 64 + cb]);
        const f16x2* rp = reinterpret_cast<const f16x2*>(&rv);
        float4 w0 = *reinterpret_cast<const float4*>(&att[cb]);
        float4 w1 = *reinterpret_cast<const float4*>(&att[cb + 4]);
        float aa[8] = {w0.x, w0.y, w0.z, w0.w, w1.x, w1.y, w1.z, w1.w};
        #pragma unroll
        for (int j = 0; j < 4; ++j) {
            r2[j]  = rp[j];
            a62[j] = f16x2{(_Float16)(0.6f * aa[2 * j]), (_Float16)(0.6f * aa[2 * j + 1])};
            a42[j] = f16x2{(_Float16)(0.4f * aa[2 * j]), (_Float16)(0.4f * aa[2 * j + 1])};
        }
    }

    float acc[8], l, m;
    {
        uint4 sv = *reinterpret_cast<const uint4*>(&C16[(size_t)i * 128 + cb]);
        const f16x2* u2 = reinterpret_cast<const f16x2*>(&sv);
        float p = 0.f;
        #pragma unroll
        for (int j = 0; j < 4; ++j) {
            f16x2 v2 = u2[j] + r2[j];
            p = __builtin_amdgcn_fdot2(a62[j], v2, p, false);
            p = __builtin_amdgcn_fdot2(a42[j], habs2(v2), p, false);
        }
        p += __shfl_xor(p, 1, 8);
        p += __shfl_xor(p, 2, 8);
        p += __shfl_xor(p, 4, 8);
        m = p;
        l = es ? 0.f : 1.f;
        #pragma unroll
        for (int j = 0; j < 4; ++j) {
            acc[2 * j]     = es ? 0.f : (float)u2[j][0];
            acc[2 * j + 1] = es ? 0.f : (float)u2[j][1];
        }
    }

    int start = row_ptr[i], end = row_ptr[i + 1];

    int kk = start + es;
    int s = (kk < end) ? csr[kk] : i;
    uint4 cu = *reinterpret_cast<const uint4*>(&C16[(size_t)s * 128 + cb]);

    for (int k = start; k < end; k += 8) {
        int nk = k + 8 + es;
        int tn = (nk < end) ? csr[nk] : i;
        uint4 nu = *reinterpret_cast<const uint4*>(&C16[(size_t)tn * 128 + cb]);

        const f16x2* u2 = reinterpret_cast<const f16x2*>(&cu);
        float p = 0.f;
        #pragma unroll
        for (int j = 0; j < 4; ++j) {
            f16x2 v2 = u2[j] + r2[j];
            p = __builtin_amdgcn_fdot2(a62[j], v2, p, false);
            p = __builtin_amdgcn_fdot2(a42[j], habs2(v2), p, false);
        }
        p += __shfl_xor(p, 1, 8);
        p += __shfl_xor(p, 2, 8);
        p += __shfl_xor(p, 4, 8);
        float e = (k + es < end) ? __expf(fminf(p - m, 60.f)) : 0.f;
        l += e;
        #pragma unroll
        for (int j = 0; j < 4; ++j) {
            acc[2 * j]     = fmaf(e, (float)u2[j][0], acc[2 * j]);
            acc[2 * j + 1] = fmaf(e, (float)u2[j][1], acc[2 * j + 1]);
        }

        cu = nu;
    }

    l += __shfl_xor(l, 8, 64);
    l += __shfl_xor(l, 16, 64);
    l += __shfl_xor(l, 32, 64);
    #pragma unroll
    for (int c = 0; c < 8; ++c) {
        acc[c] += __shfl_xor(acc[c], 8, 64);
        acc[c] += __shfl_xor(acc[c], 16, 64);
        acc[c] += __shfl_xor(acc[c], 32, 64);
    }

    if (es == 0) {
        float inv = 1.0f / l;
        float4 bb0 = *reinterpret_cast<const float4*>(&bias[cb]);
        float4 bb1 = *reinterpret_cast<const float4*>(&bias[cb + 4]);
        float4 o0, o1;
        o0.x = fmaf(acc[0], inv, bb0.x);
        o0.y = fmaf(acc[1], inv, bb0.y);
        o0.z = fmaf(acc[2], inv, bb0.z);
        o0.w = fmaf(acc[3], inv, bb0.w);
        o1.x = fmaf(acc[4], inv, bb1.x);
        o1.y = fmaf(acc[5], inv, bb1.y);
        o1.z = fmaf(acc[6], inv, bb1.z);
        o1.w = fmaf(acc[7], inv, bb1.w);
        *reinterpret_cast<float4*>(&out[(size_t)i * 64 + cb]) = o0;
        *reinterpret_cast<float4*>(&out[(size_t)i * 64 + cb + 4]) = o1;
    }
}

// ---------------------------------------------------------------------------

extern "C" void kernel_launch(void* const* d_in, const int* in_sizes, int n_in,
                              void* d_out, int out_size, void* d_ws, size_t ws_size,
                              hipStream_t stream) {
    const float* x    = (const float*)d_in[0];
    const void*  ei   = d_in[1];
    const float* Wl1  = (const float*)d_in[2];
    const float* Wr1  = (const float*)d_in[3];
    const float* att1 = (const float*)d_in[4];
    const float* b1   = (const float*)d_in[5];
    const float* Wl2  = (const float*)d_in[6];
    const float* Wr2  = (const float*)d_in[7];
    const float* att2 = (const float*)d_in[8];
    const float* b2   = (const float*)d_in[9];
    const float* Wl3  = (const float*)d_in[10];
    const float* Wr3  = (const float*)d_in[11];
    const float* att3 = (const float*)d_in[12];
    const float* b3   = (const float*)d_in[13];
    float* out = (float*)d_out;

    int N = in_sizes[0] / 256;
    int E = in_sizes[1] / 2;

    char* w = (char*)d_ws;
    unsigned short* a16  = (unsigned short*)w; w += (size_t)N * 256 * 2;  // GEMM A / agg output
    __half* C16 = (__half*)w;      w += (size_t)N * 512 * 2;              // GEMM C (xl | xr)
    unsigned short* WT = (unsigned short*)w; w += (size_t)512 * 256 * 2;
    int* row_ptr = (int*)w; w += ((size_t)N + 2) * sizeof(int);
    int* deg     = (int*)w; w += (size_t)N * sizeof(int);
    int* csr     = (int*)w; w += (size_t)E * sizeof(int);
    int* flag    = (int*)w; w += 256;
    int* partial = (int*)w; w += 256;

    // --- CSR build ---
    detect_i64_kernel<<<1, 256, 0, stream>>>((const unsigned int*)ei, E, flag);
    hipMemsetAsync(deg, 0, (size_t)N * sizeof(int), stream);
    count_deg_kernel<<<(E + 255) / 256, 256, 0, stream>>>(ei, E, flag, deg);
    int nb = (N + 1023) / 1024;
    scan_block_kernel<<<nb, 1024, 0, stream>>>(deg, row_ptr, partial, N);
    scan_top_kernel<<<1, 64, 0, stream>>>(partial, nb);
    scan_addoff_kernel<<<(N + 255) / 256, 256, 0, stream>>>(row_ptr, partial, N);
    hipMemsetAsync(deg, 0, (size_t)N * sizeof(int), stream);
    scatter_kernel<<<(E + 255) / 256, 256, 0, stream>>>(ei, E, flag, row_ptr, deg, csr);

    int gemm_gx = (N + 127) / 128;
    int agg_g = (N + 3) / 4;

    // --- Layer 1 ---
    to_f16_kernel<<<((N * 256 / 4) + 255) / 256, 256, 0, stream>>>(x, N * 256 / 4, a16);
    splitT_w_kernel<<<dim3(256, 2), 256, 0, stream>>>(Wl1, Wr1, 256, WT);
    gemm_mfma_kernel<<<dim3(gemm_gx, 4), 256, 0, stream>>>(a16, WT, C16, N, 256);
    agg_h8_kernel<<<agg_g, 256, 0, stream>>>(C16, att1, b1, row_ptr, csr, a16, N);

    // --- Layer 2 ---
    splitT_w_kernel<<<dim3(256, 2), 256, 0, stream>>>(Wl2, Wr2, 256, WT);
    gemm_mfma_kernel<<<dim3(gemm_gx, 4), 256, 0, stream>>>(a16, WT, C16, N, 256);
    agg_h8_kernel<<<agg_g, 256, 0, stream>>>(C16, att2, b2, row_ptr, csr, a16, N);

    // --- Layer 3 ---
    splitT_w_kernel<<<dim3(256, 1), 256, 0, stream>>>(Wl3, Wr3, 64, WT);
    gemm_mfma_kernel<<<dim3(gemm_gx, 1), 256, 0, stream>>>(a16, WT, C16, N, 64);
    agg_h1_kernel<<<agg_g, 256, 0, stream>>>(C16, att3, b3, row_ptr, csr, out, N);
}